// Round 6
// baseline (472.430 us; speedup 1.0000x reference)
//
#include <hip/hip_runtime.h>
#include <math.h>

#define L_SEQ 16384
#define BATCH 2
#define BL (BATCH * L_SEQ)      // 32768
#define DIN 256                 // D_INNER
#define DIMC 128                // DIM
#define NST 16                  // D_STATE
#define DTR 8                   // DT_RANK
#define CL 64                   // chunk length for scan
#define NC (L_SEQ / CL)         // 256 chunks per batch

// ---------------- K0a: layernorm stats (mean, rstd) per position ----------------
__global__ __launch_bounds__(256) void k_ln_stats(const float* __restrict__ x,
                                                  float* __restrict__ mu,
                                                  float* __restrict__ rstd) {
    int p = blockIdx.x * 256 + threadIdx.x;   // 0..BL-1
    int b = p / L_SEQ, l = p % L_SEQ;
    const float* xb = x + (size_t)b * DIMC * L_SEQ + l;
    float s = 0.f, s2 = 0.f;
    for (int c = 0; c < DIMC; c++) {
        float v = xb[(size_t)c * L_SEQ];
        s += v; s2 += v * v;
    }
    float m = s * (1.f / DIMC);
    float var = s2 * (1.f / DIMC) - m * m;
    mu[p] = m;
    rstd[p] = rsqrtf(var + 1e-6f);
}

// ---------------- K0b: weight prep — fold LN weight into w1, pre-transpose w1/wx/wo ----
// w1t[c][o] = w1[o][c]*nw[c];  g[o] = sum_c w1t[c][o];  h[o] = sum_c w1[o][c]*nb[c]
// wxt[c][o] = wx[o][c] (o<40 else 0);  wot[k][c] = wo[c][k]
__global__ __launch_bounds__(256) void k_prep(const float* __restrict__ w1,
                                              const float* __restrict__ nw,
                                              const float* __restrict__ nb,
                                              const float* __restrict__ wx,
                                              const float* __restrict__ wo,
                                              float* __restrict__ w1t,
                                              float* __restrict__ g,
                                              float* __restrict__ h,
                                              float* __restrict__ wxt,
                                              float* __restrict__ wot) {
    int id = blockIdx.x * 256 + threadIdx.x;   // grid 2 -> 0..511
    if (id < 512) {
        float gs = 0.f, hs = 0.f;
        for (int c = 0; c < 128; c++) {
            float w = w1[id * 128 + c];
            float wn = w * nw[c];
            w1t[c * 512 + id] = wn;
            gs += wn; hs += w * nb[c];
        }
        g[id] = gs; h[id] = hs;
    }
    if (id < 64) {
        for (int c = 0; c < 256; c++)
            wxt[c * 64 + id] = (id < 40) ? wx[id * 256 + c] : 0.f;
    }
    if (id < 256) {
        for (int c = 0; c < 128; c++)
            wot[id * 128 + c] = wo[c * 256 + id];
    }
}

// ---------------- K1: in_proj GEMM on RAW x (LN folded into weights) + conv+silu epilogue ----
// grid dim3(8, BL/64): o-blocks fastest -> 8 dispatch-adjacent blocks share one x-tile (L2).
// As[c][i], i=0..67 covers positions l0-4..l0+63 (17 aligned float4/row; conv halo free).
// Epilogue: xz = acc*rs - mu*rs*g_o + h_o. xs blocks run causal conv+silu in an LDS
// overlay and write xin; z blocks write zbuf. All staging conflict-free & coalesced.
__global__ __launch_bounds__(256) void k_inproj(const float* __restrict__ x,
                                                const float* __restrict__ mu,
                                                const float* __restrict__ rstd,
                                                const float* __restrict__ w1t,
                                                const float* __restrict__ g,
                                                const float* __restrict__ h,
                                                const float* __restrict__ cw,
                                                const float* __restrict__ cb,
                                                float* __restrict__ xin,
                                                float* __restrict__ zbuf) {
    __shared__ float As[128 * 68];   // [c][i]
    __shared__ float Bs[128 * 68];   // [c][o]; reused post-GEMM as xs overlay [i][o]
    int o0 = blockIdx.x * 64;
    int bl0 = blockIdx.y * 64;
    int b = bl0 / L_SEQ, l0 = bl0 % L_SEQ;
    int tid = threadIdx.x;
    int tx = tid & 15, ty = tid >> 4;

    for (int idx = tid; idx < 128 * 17; idx += 256) {
        int c = idx / 17, q = idx - c * 17;
        int off = l0 - 4 + q * 4;
        if (off < 0) off = 0;                      // only q==0 at l0==0; halo zeroed later
        float4 v = *(const float4*)&x[(size_t)(b * 128 + c) * L_SEQ + off];
        *(float4*)&As[c * 68 + q * 4] = v;
    }
    for (int idx = tid; idx < 128 * 16; idx += 256) {
        int c = idx >> 4, q = idx & 15;
        float4 v = *(const float4*)&w1t[(size_t)c * 512 + o0 + q * 4];
        *(float4*)&Bs[c * 68 + q * 4] = v;
    }
    __syncthreads();

    float acc[4][4] = {};
    for (int c = 0; c < 128; c++) {
        float4 av = *(const float4*)&As[c * 68 + 4 + ty * 4];
        float4 bv = *(const float4*)&Bs[c * 68 + tx * 4];
        float a[4] = {av.x, av.y, av.z, av.w};
        float bb[4] = {bv.x, bv.y, bv.z, bv.w};
        #pragma unroll
        for (int ii = 0; ii < 4; ii++)
            #pragma unroll
            for (int jj = 0; jj < 4; jj++) acc[ii][jj] += a[ii] * bb[jj];
    }
    // Halo dot products (3 halo positions x 64 outputs); As col read is wave-broadcast
    float hacc = 0.f;
    if (o0 < 256 && tid < 192) {
        int hp = tid >> 6, o = tid & 63;
        for (int c = 0; c < 128; c++) hacc += As[c * 68 + 1 + hp] * Bs[c * 68 + o];
    }

    // LN correction
    float go[4], ho[4];
    #pragma unroll
    for (int jj = 0; jj < 4; jj++) { go[jj] = g[o0 + tx * 4 + jj]; ho[jj] = h[o0 + tx * 4 + jj]; }
    float xzv[4][4];
    #pragma unroll
    for (int ii = 0; ii < 4; ii++) {
        int p = bl0 + ty * 4 + ii;
        float m = mu[p], r = rstd[p];
        #pragma unroll
        for (int jj = 0; jj < 4; jj++) xzv[ii][jj] = acc[ii][jj] * r - m * r * go[jj] + ho[jj];
    }

    if (o0 < 256) {
        __syncthreads();                 // done reading As/Bs; reuse Bs as overlay
        float* xsT = Bs;                 // [i (0..66)][o], i = j+3 for main j, 0..2 halo
        #pragma unroll
        for (int ii = 0; ii < 4; ii++)
            #pragma unroll
            for (int jj = 0; jj < 4; jj++)
                xsT[(3 + ty * 4 + ii) * 68 + tx * 4 + jj] = xzv[ii][jj];
        if (tid < 192) {
            int hp = tid >> 6, o = tid & 63;
            float hv = 0.f;
            if (l0 > 0) {
                int ph = bl0 - 3 + hp;
                float m = mu[ph], r = rstd[ph];
                hv = hacc * r - m * r * g[o0 + o] + h[o0 + o];
            }
            xsT[hp * 68 + o] = hv;
        }
        __syncthreads();
        // causal conv (k=4) + silu, write xin
        int ob = o0 + tx * 4;
        float w[4][4], bias4[4];
        #pragma unroll
        for (int jj = 0; jj < 4; jj++) {
            bias4[jj] = cb[ob + jj];
            #pragma unroll
            for (int k = 0; k < 4; k++) w[jj][k] = cw[(ob + jj) * 4 + k];
        }
        #pragma unroll
        for (int ii = 0; ii < 4; ii++) {
            int j = ty * 4 + ii;
            float v[4];
            #pragma unroll
            for (int jj = 0; jj < 4; jj++) {
                float a = bias4[jj];
                #pragma unroll
                for (int k = 0; k < 4; k++)
                    a += xsT[(j + k) * 68 + tx * 4 + jj] * w[jj][k];
                float sig = 1.f / (1.f + __expf(-a));
                v[jj] = a * sig;
            }
            *(float4*)&xin[(size_t)(bl0 + j) * 256 + ob] = make_float4(v[0], v[1], v[2], v[3]);
        }
    } else {
        #pragma unroll
        for (int ii = 0; ii < 4; ii++) {
            int p = bl0 + ty * 4 + ii;
            float4 v = make_float4(xzv[ii][0], xzv[ii][1], xzv[ii][2], xzv[ii][3]);
            *(float4*)&zbuf[(size_t)p * 256 + (o0 - 256) + tx * 4] = v;
        }
    }
}

// ---------------- K3: x_proj GEMM (256->40, padded 64) + fused dt_proj + softplus ----------------
__global__ __launch_bounds__(256) void k_xproj(const float* __restrict__ xin,
                                               const float* __restrict__ wxt,
                                               const float* __restrict__ wdt,
                                               const float* __restrict__ bdt,
                                               float* __restrict__ dtb,
                                               float* __restrict__ Bmb,
                                               float* __restrict__ Cmb) {
    __shared__ float Xs[64 * 68];   // [c_local][pos_local]
    __shared__ float Ws[64 * 68];   // [c_local][o]
    __shared__ float Dt8[64 * 8];
    int bl0 = blockIdx.x * 64;
    int tid = threadIdx.x;
    int tx = tid & 15, ty = tid >> 4;

    float acc[4][4] = {};
    for (int c0 = 0; c0 < 256; c0 += 64) {
        __syncthreads();
        for (int idx = tid; idx < 64 * 16; idx += 256) {
            int i = idx >> 4, q = idx & 15;
            float4 v = *(const float4*)&xin[(size_t)(bl0 + i) * 256 + c0 + q * 4];
            Xs[(q * 4 + 0) * 68 + i] = v.x;
            Xs[(q * 4 + 1) * 68 + i] = v.y;
            Xs[(q * 4 + 2) * 68 + i] = v.z;
            Xs[(q * 4 + 3) * 68 + i] = v.w;
        }
        for (int idx = tid; idx < 64 * 16; idx += 256) {
            int c = idx >> 4, q = idx & 15;
            float4 v = *(const float4*)&wxt[(size_t)(c0 + c) * 64 + q * 4];
            *(float4*)&Ws[c * 68 + q * 4] = v;
        }
        __syncthreads();
        for (int c = 0; c < 64; c++) {
            float4 av = *(const float4*)&Xs[c * 68 + ty * 4];
            float4 bv = *(const float4*)&Ws[c * 68 + tx * 4];
            float a[4] = {av.x, av.y, av.z, av.w};
            float bb[4] = {bv.x, bv.y, bv.z, bv.w};
            #pragma unroll
            for (int ii = 0; ii < 4; ii++)
                #pragma unroll
                for (int jj = 0; jj < 4; jj++) acc[ii][jj] += a[ii] * bb[jj];
        }
    }

    __syncthreads();
    if (tx < 2) {
        #pragma unroll
        for (int ii = 0; ii < 4; ii++)
            #pragma unroll
            for (int jj = 0; jj < 4; jj++)
                Dt8[(ty * 4 + ii) * 8 + tx * 4 + jj] = acc[ii][jj];
    } else if (tx < 6) {
        #pragma unroll
        for (int ii = 0; ii < 4; ii++) {
            size_t p = (size_t)(bl0 + ty * 4 + ii);
            float4 v = make_float4(acc[ii][0], acc[ii][1], acc[ii][2], acc[ii][3]);
            *(float4*)&Bmb[p * 16 + (tx - 2) * 4] = v;
        }
    } else if (tx < 10) {
        #pragma unroll
        for (int ii = 0; ii < 4; ii++) {
            size_t p = (size_t)(bl0 + ty * 4 + ii);
            float4 v = make_float4(acc[ii][0], acc[ii][1], acc[ii][2], acc[ii][3]);
            *(float4*)&Cmb[p * 16 + (tx - 6) * 4] = v;
        }
    }
    __syncthreads();

    int d = tid;
    float bias = bdt[d];
    float w8[8];
    #pragma unroll
    for (int r = 0; r < 8; r++) w8[r] = wdt[d * 8 + r];
    for (int p = 0; p < 64; p++) {
        float4 xa = *(float4*)&Dt8[p * 8];
        float4 xb = *(float4*)&Dt8[p * 8 + 4];
        float a = bias;
        a += xa.x * w8[0] + xa.y * w8[1] + xa.z * w8[2] + xa.w * w8[3];
        a += xb.x * w8[4] + xb.y * w8[5] + xb.z * w8[6] + xb.w * w8[7];
        float sp = (a > 20.f) ? a : log1pf(__expf(a));
        dtb[(size_t)(bl0 + p) * 256 + d] = sp;
    }
}

// ---------------- K4a: scan phase 1 — per-chunk products & local states ----------------
__global__ __launch_bounds__(256) void k_scan1(const float* __restrict__ dtb,
                                               const float* __restrict__ xin,
                                               const float* __restrict__ Bmb,
                                               const float* __restrict__ Alog,
                                               float* __restrict__ Pb,
                                               float* __restrict__ Sb) {
    int blk = blockIdx.x;            // BATCH*NC blocks
    int b = blk / NC, ch = blk % NC;
    int d = threadIdx.x;
    int t0 = ch * CL;
    __shared__ float Bs[CL * 16];
    for (int idx = threadIdx.x; idx < CL * 16; idx += 256)
        Bs[idx] = Bmb[((size_t)(b * L_SEQ + t0)) * 16 + idx];
    float Ar[16];
    #pragma unroll
    for (int n = 0; n < 16; n++) Ar[n] = -__expf(Alog[d * 16 + n]);
    float P[16], S[16];
    #pragma unroll
    for (int n = 0; n < 16; n++) { P[n] = 1.f; S[n] = 0.f; }
    __syncthreads();
    for (int i = 0; i < CL; i++) {
        size_t p = (size_t)(b * L_SEQ + t0 + i);
        float dtv = dtb[p * 256 + d];
        float xv  = xin[p * 256 + d];
        float du = dtv * xv;
        #pragma unroll
        for (int n = 0; n < 16; n++) {
            float a = __expf(dtv * Ar[n]);
            P[n] *= a;
            S[n] = a * S[n] + du * Bs[i * 16 + n];
        }
    }
    size_t base = ((size_t)(b * NC + ch) * 16) * 256 + d;
    #pragma unroll
    for (int n = 0; n < 16; n++) {
        Pb[base + (size_t)n * 256] = P[n];
        Sb[base + (size_t)n * 256] = S[n];
    }
}

// ---------------- K4b: scan phase 2 — sequential over chunks, Sb becomes h_start ----------------
__global__ __launch_bounds__(256) void k_scan2(const float* __restrict__ Pb,
                                               float* __restrict__ Sb) {
    int id = blockIdx.x * 256 + threadIdx.x;  // 0..8191: (b,n,d)
    int d = id & 255;
    int n = (id >> 8) & 15;
    int b = id >> 12;
    float h = 0.f;
    #pragma unroll 4
    for (int c = 0; c < NC; c++) {
        size_t ix = (((size_t)(b * NC + c) * 16) + n) * 256 + d;
        float Pv = Pb[ix];
        float Sv = Sb[ix];
        Sb[ix] = h;          // h_start for chunk c
        h = Pv * h + Sv;
    }
}

// ---------------- K4c: scan phase 3 — replay chunk, fuse D-skip + silu(z) gate ----------------
__global__ __launch_bounds__(256) void k_scan3(const float* __restrict__ dtb,
                                               const float* __restrict__ xin,
                                               const float* __restrict__ Bmb,
                                               const float* __restrict__ Cmb,
                                               const float* __restrict__ Alog,
                                               const float* __restrict__ Sb,
                                               const float* __restrict__ Dp,
                                               const float* __restrict__ zbuf,
                                               float* __restrict__ yg) {
    int blk = blockIdx.x;
    int b = blk / NC, ch = blk % NC;
    int d = threadIdx.x;
    int t0 = ch * CL;
    __shared__ float Bs[CL * 16], Cs[CL * 16];
    for (int idx = threadIdx.x; idx < CL * 16; idx += 256) {
        Bs[idx] = Bmb[((size_t)(b * L_SEQ + t0)) * 16 + idx];
        Cs[idx] = Cmb[((size_t)(b * L_SEQ + t0)) * 16 + idx];
    }
    float Ar[16], h[16];
    #pragma unroll
    for (int n = 0; n < 16; n++) Ar[n] = -__expf(Alog[d * 16 + n]);
    size_t base = ((size_t)(b * NC + ch) * 16) * 256 + d;
    #pragma unroll
    for (int n = 0; n < 16; n++) h[n] = Sb[base + (size_t)n * 256];
    float Dv = Dp[d];
    __syncthreads();
    for (int i = 0; i < CL; i++) {
        size_t p = (size_t)(b * L_SEQ + t0 + i);
        float dtv = dtb[p * 256 + d];
        float xv  = xin[p * 256 + d];
        float du = dtv * xv;
        float y = 0.f;
        #pragma unroll
        for (int n = 0; n < 16; n++) {
            float a = __expf(dtv * Ar[n]);
            h[n] = a * h[n] + du * Bs[i * 16 + n];
            y += h[n] * Cs[i * 16 + n];
        }
        float zv = zbuf[p * 256 + d];
        float sig = 1.f / (1.f + __expf(-zv));
        yg[p * 256 + d] = (y + xv * Dv) * (zv * sig);
    }
}

// ---------------- K5: out_proj GEMM with transposed output ----------------
__global__ __launch_bounds__(256) void k_outproj(const float* __restrict__ yg,
                                                 const float* __restrict__ wot,
                                                 float* __restrict__ out) {
    // grid: (BL/64, 2)
    __shared__ float As[64 * 68];  // [k][t_local]
    __shared__ float Bs[64 * 68];  // [k][c_local]
    int bl0 = blockIdx.x * 64;
    int b = bl0 / L_SEQ;
    int t0 = bl0 % L_SEQ;
    int c0 = blockIdx.y * 64;
    int tid = threadIdx.x;
    int tx = tid & 15, ty = tid >> 4;   // tx -> t (coalesced out writes), ty -> c

    float acc[4][4] = {};               // [t_off][c_off]
    for (int k0 = 0; k0 < 256; k0 += 64) {
        __syncthreads();
        for (int idx = tid; idx < 64 * 16; idx += 256) {
            int t = idx >> 4, q = idx & 15;
            float4 v = *(const float4*)&yg[(size_t)(bl0 + t) * 256 + k0 + q * 4];
            As[(q * 4 + 0) * 68 + t] = v.x;
            As[(q * 4 + 1) * 68 + t] = v.y;
            As[(q * 4 + 2) * 68 + t] = v.z;
            As[(q * 4 + 3) * 68 + t] = v.w;
        }
        for (int idx = tid; idx < 64 * 16; idx += 256) {
            int kk = idx >> 4, q = idx & 15;
            float4 v = *(const float4*)&wot[(size_t)(k0 + kk) * 128 + c0 + q * 4];
            *(float4*)&Bs[kk * 68 + q * 4] = v;
        }
        __syncthreads();
        for (int k = 0; k < 64; k++) {
            float4 av = *(const float4*)&As[k * 68 + tx * 4];
            float4 bv = *(const float4*)&Bs[k * 68 + ty * 4];
            float a[4] = {av.x, av.y, av.z, av.w};
            float bb[4] = {bv.x, bv.y, bv.z, bv.w};
            #pragma unroll
            for (int ii = 0; ii < 4; ii++)
                #pragma unroll
                for (int jj = 0; jj < 4; jj++) acc[ii][jj] += a[ii] * bb[jj];
        }
    }
    #pragma unroll
    for (int jj = 0; jj < 4; jj++) {
        int c = c0 + ty * 4 + jj;
        float4 v = make_float4(acc[0][jj], acc[1][jj], acc[2][jj], acc[3][jj]);
        *(float4*)&out[((size_t)(b * 128 + c)) * L_SEQ + t0 + tx * 4] = v;
    }
}

extern "C" void kernel_launch(void* const* d_in, const int* in_sizes, int n_in,
                              void* d_out, int out_size, void* d_ws, size_t ws_size,
                              hipStream_t stream) {
    const float* x    = (const float*)d_in[0];
    const float* nw   = (const float*)d_in[1];
    const float* nb   = (const float*)d_in[2];
    const float* w1   = (const float*)d_in[3];
    const float* cw   = (const float*)d_in[4];
    const float* cb   = (const float*)d_in[5];
    const float* wx   = (const float*)d_in[6];
    const float* wdt  = (const float*)d_in[7];
    const float* bdt  = (const float*)d_in[8];
    const float* Alog = (const float*)d_in[9];
    const float* Dp   = (const float*)d_in[10];
    const float* wo   = (const float*)d_in[11];
    float* out = (float*)d_out;

    float* ws   = (float*)d_ws;
    float* zbuf = ws;                       // BL*256
    float* xin  = zbuf + (size_t)BL * 256;  // BL*256
    float* dtb  = xin + (size_t)BL * 256;   // BL*256
    float* Bmb  = dtb + (size_t)BL * 256;   // BL*16
    float* Cmb  = Bmb + (size_t)BL * 16;    // BL*16
    float* Pb   = Cmb + (size_t)BL * 16;    // BATCH*NC*16*256
    float* Sb   = Pb + (size_t)BATCH * NC * 16 * 256;
    float* yg   = Sb + (size_t)BATCH * NC * 16 * 256;  // BL*256
    float* mu   = yg + (size_t)BL * 256;    // BL
    float* rstd = mu + BL;                  // BL
    float* w1t  = rstd + BL;                // 128*512
    float* g    = w1t + 128 * 512;          // 512
    float* h    = g + 512;                  // 512
    float* wxt  = h + 512;                  // 256*64
    float* wot  = wxt + 256 * 64;           // 256*128

    k_prep<<<2, 256, 0, stream>>>(w1, nw, nb, wx, wo, w1t, g, h, wxt, wot);
    k_ln_stats<<<BL / 256, 256, 0, stream>>>(x, mu, rstd);
    k_inproj<<<dim3(8, BL / 64), 256, 0, stream>>>(x, mu, rstd, w1t, g, h, cw, cb, xin, zbuf);
    k_xproj<<<BL / 64, 256, 0, stream>>>(xin, wxt, wdt, bdt, dtb, Bmb, Cmb);
    k_scan1<<<BATCH * NC, 256, 0, stream>>>(dtb, xin, Bmb, Alog, Pb, Sb);
    k_scan2<<<8192 / 256, 256, 0, stream>>>(Pb, Sb);
    k_scan3<<<BATCH * NC, 256, 0, stream>>>(dtb, xin, Bmb, Cmb, Alog, Sb, Dp, zbuf, yg);
    k_outproj<<<dim3(BL / 64, 2), 256, 0, stream>>>(yg, wot, out);
}

// Round 7
// 455.547 us; speedup vs baseline: 1.0371x; 1.0371x over previous
//
#include <hip/hip_runtime.h>
#include <math.h>

#define L_SEQ 16384
#define BATCH 2
#define BL (BATCH * L_SEQ)      // 32768
#define DIN 256                 // D_INNER
#define DIMC 128                // DIM
#define NST 16                  // D_STATE
#define DTR 8                   // DT_RANK
#define CL 64                   // chunk length for scan
#define NC (L_SEQ / CL)         // 256 chunks per batch

// ---------------- K0a: layernorm stats (mean, rstd) per position ----------------
__global__ __launch_bounds__(256) void k_ln_stats(const float* __restrict__ x,
                                                  float* __restrict__ mu,
                                                  float* __restrict__ rstd) {
    int p = blockIdx.x * 256 + threadIdx.x;   // 0..BL-1
    int b = p / L_SEQ, l = p % L_SEQ;
    const float* xb = x + (size_t)b * DIMC * L_SEQ + l;
    float s = 0.f, s2 = 0.f;
    for (int c = 0; c < DIMC; c++) {
        float v = xb[(size_t)c * L_SEQ];
        s += v; s2 += v * v;
    }
    float m = s * (1.f / DIMC);
    float var = s2 * (1.f / DIMC) - m * m;
    mu[p] = m;
    rstd[p] = rsqrtf(var + 1e-6f);
}

// ---------------- K0b: weight prep — fold LN weight into w1, pre-transpose w1/wx/wo ----
__global__ __launch_bounds__(256) void k_prep(const float* __restrict__ w1,
                                              const float* __restrict__ nw,
                                              const float* __restrict__ nb,
                                              const float* __restrict__ wx,
                                              const float* __restrict__ wo,
                                              float* __restrict__ w1t,
                                              float* __restrict__ g,
                                              float* __restrict__ h,
                                              float* __restrict__ wxt,
                                              float* __restrict__ wot) {
    int id = blockIdx.x * 256 + threadIdx.x;   // grid 2 -> 0..511
    if (id < 512) {
        float gs = 0.f, hs = 0.f;
        for (int c = 0; c < 128; c++) {
            float w = w1[id * 128 + c];
            float wn = w * nw[c];
            w1t[c * 512 + id] = wn;
            gs += wn; hs += w * nb[c];
        }
        g[id] = gs; h[id] = hs;
    }
    if (id < 64) {
        for (int c = 0; c < 256; c++)
            wxt[c * 64 + id] = (id < 40) ? wx[id * 256 + c] : 0.f;
    }
    if (id < 256) {
        for (int c = 0; c < 128; c++)
            wot[id * 128 + c] = wo[c * 256 + id];
    }
}

// ---------------- K1: in_proj GEMM on RAW x (LN folded into weights) + conv+silu epilogue ----
// grid dim3(BL/64, 8): POSITION-FASTEST. Linear id = o*512+pos -> XCD = pos%8, so the
// 8 o-blocks sharing one x-tile all land on the SAME XCD, and each XCD's x footprint is
// a disjoint 2.2 MB slice that fits its 4 MB private L2 (x fetched from HBM once).
// (o-fastest ordering round-robins the sharers across XCDs: 8x x traffic — measured R6.)
__global__ __launch_bounds__(256) void k_inproj(const float* __restrict__ x,
                                                const float* __restrict__ mu,
                                                const float* __restrict__ rstd,
                                                const float* __restrict__ w1t,
                                                const float* __restrict__ g,
                                                const float* __restrict__ h,
                                                const float* __restrict__ cw,
                                                const float* __restrict__ cb,
                                                float* __restrict__ xin,
                                                float* __restrict__ zbuf) {
    __shared__ float As[128 * 68];   // [c][i]
    __shared__ float Bs[128 * 68];   // [c][o]; reused post-GEMM as xs overlay [i][o]
    int bl0 = blockIdx.x * 64;
    int o0 = blockIdx.y * 64;
    int b = bl0 / L_SEQ, l0 = bl0 % L_SEQ;
    int tid = threadIdx.x;
    int tx = tid & 15, ty = tid >> 4;

    for (int idx = tid; idx < 128 * 17; idx += 256) {
        int c = idx / 17, q = idx - c * 17;
        int off = l0 - 4 + q * 4;
        if (off < 0) off = 0;                      // only q==0 at l0==0; halo zeroed later
        float4 v = *(const float4*)&x[(size_t)(b * 128 + c) * L_SEQ + off];
        *(float4*)&As[c * 68 + q * 4] = v;
    }
    for (int idx = tid; idx < 128 * 16; idx += 256) {
        int c = idx >> 4, q = idx & 15;
        float4 v = *(const float4*)&w1t[(size_t)c * 512 + o0 + q * 4];
        *(float4*)&Bs[c * 68 + q * 4] = v;
    }
    __syncthreads();

    float acc[4][4] = {};
    for (int c = 0; c < 128; c++) {
        float4 av = *(const float4*)&As[c * 68 + 4 + ty * 4];
        float4 bv = *(const float4*)&Bs[c * 68 + tx * 4];
        float a[4] = {av.x, av.y, av.z, av.w};
        float bb[4] = {bv.x, bv.y, bv.z, bv.w};
        #pragma unroll
        for (int ii = 0; ii < 4; ii++)
            #pragma unroll
            for (int jj = 0; jj < 4; jj++) acc[ii][jj] += a[ii] * bb[jj];
    }
    // Halo dot products (3 halo positions x 64 outputs); As col read is wave-broadcast
    float hacc = 0.f;
    if (o0 < 256 && tid < 192) {
        int hp = tid >> 6, o = tid & 63;
        for (int c = 0; c < 128; c++) hacc += As[c * 68 + 1 + hp] * Bs[c * 68 + o];
    }

    // LN correction: xz = acc*r - mu*r*g_o + h_o
    float go[4], ho[4];
    #pragma unroll
    for (int jj = 0; jj < 4; jj++) { go[jj] = g[o0 + tx * 4 + jj]; ho[jj] = h[o0 + tx * 4 + jj]; }
    float xzv[4][4];
    #pragma unroll
    for (int ii = 0; ii < 4; ii++) {
        int p = bl0 + ty * 4 + ii;
        float m = mu[p], r = rstd[p];
        #pragma unroll
        for (int jj = 0; jj < 4; jj++) xzv[ii][jj] = acc[ii][jj] * r - m * r * go[jj] + ho[jj];
    }

    if (o0 < 256) {
        __syncthreads();                 // done reading As/Bs; reuse Bs as overlay
        float* xsT = Bs;                 // [i (0..66)][o], i = j+3 for main j, 0..2 halo
        #pragma unroll
        for (int ii = 0; ii < 4; ii++)
            #pragma unroll
            for (int jj = 0; jj < 4; jj++)
                xsT[(3 + ty * 4 + ii) * 68 + tx * 4 + jj] = xzv[ii][jj];
        if (tid < 192) {
            int hp = tid >> 6, o = tid & 63;
            float hv = 0.f;
            if (l0 > 0) {
                int ph = bl0 - 3 + hp;
                float m = mu[ph], r = rstd[ph];
                hv = hacc * r - m * r * g[o0 + o] + h[o0 + o];
            }
            xsT[hp * 68 + o] = hv;
        }
        __syncthreads();
        // causal conv (k=4) + silu, write xin
        int ob = o0 + tx * 4;
        float w[4][4], bias4[4];
        #pragma unroll
        for (int jj = 0; jj < 4; jj++) {
            bias4[jj] = cb[ob + jj];
            #pragma unroll
            for (int k = 0; k < 4; k++) w[jj][k] = cw[(ob + jj) * 4 + k];
        }
        #pragma unroll
        for (int ii = 0; ii < 4; ii++) {
            int j = ty * 4 + ii;
            float v[4];
            #pragma unroll
            for (int jj = 0; jj < 4; jj++) {
                float a = bias4[jj];
                #pragma unroll
                for (int k = 0; k < 4; k++)
                    a += xsT[(j + k) * 68 + tx * 4 + jj] * w[jj][k];
                float sig = 1.f / (1.f + __expf(-a));
                v[jj] = a * sig;
            }
            *(float4*)&xin[(size_t)(bl0 + j) * 256 + ob] = make_float4(v[0], v[1], v[2], v[3]);
        }
    } else {
        #pragma unroll
        for (int ii = 0; ii < 4; ii++) {
            int p = bl0 + ty * 4 + ii;
            float4 v = make_float4(xzv[ii][0], xzv[ii][1], xzv[ii][2], xzv[ii][3]);
            *(float4*)&zbuf[(size_t)p * 256 + (o0 - 256) + tx * 4] = v;
        }
    }
}

// ---------------- K3: x_proj GEMM (256->40, padded 64) + fused dt_proj + softplus ----------------
__global__ __launch_bounds__(256) void k_xproj(const float* __restrict__ xin,
                                               const float* __restrict__ wxt,
                                               const float* __restrict__ wdt,
                                               const float* __restrict__ bdt,
                                               float* __restrict__ dtb,
                                               float* __restrict__ Bmb,
                                               float* __restrict__ Cmb) {
    __shared__ float Xs[64 * 68];   // [c_local][pos_local]
    __shared__ float Ws[64 * 68];   // [c_local][o]
    __shared__ float Dt8[64 * 8];
    int bl0 = blockIdx.x * 64;
    int tid = threadIdx.x;
    int tx = tid & 15, ty = tid >> 4;

    float acc[4][4] = {};
    for (int c0 = 0; c0 < 256; c0 += 64) {
        __syncthreads();
        for (int idx = tid; idx < 64 * 16; idx += 256) {
            int i = idx >> 4, q = idx & 15;
            float4 v = *(const float4*)&xin[(size_t)(bl0 + i) * 256 + c0 + q * 4];
            Xs[(q * 4 + 0) * 68 + i] = v.x;
            Xs[(q * 4 + 1) * 68 + i] = v.y;
            Xs[(q * 4 + 2) * 68 + i] = v.z;
            Xs[(q * 4 + 3) * 68 + i] = v.w;
        }
        for (int idx = tid; idx < 64 * 16; idx += 256) {
            int c = idx >> 4, q = idx & 15;
            float4 v = *(const float4*)&wxt[(size_t)(c0 + c) * 64 + q * 4];
            *(float4*)&Ws[c * 68 + q * 4] = v;
        }
        __syncthreads();
        for (int c = 0; c < 64; c++) {
            float4 av = *(const float4*)&Xs[c * 68 + ty * 4];
            float4 bv = *(const float4*)&Ws[c * 68 + tx * 4];
            float a[4] = {av.x, av.y, av.z, av.w};
            float bb[4] = {bv.x, bv.y, bv.z, bv.w};
            #pragma unroll
            for (int ii = 0; ii < 4; ii++)
                #pragma unroll
                for (int jj = 0; jj < 4; jj++) acc[ii][jj] += a[ii] * bb[jj];
        }
    }

    __syncthreads();
    if (tx < 2) {
        #pragma unroll
        for (int ii = 0; ii < 4; ii++)
            #pragma unroll
            for (int jj = 0; jj < 4; jj++)
                Dt8[(ty * 4 + ii) * 8 + tx * 4 + jj] = acc[ii][jj];
    } else if (tx < 6) {
        #pragma unroll
        for (int ii = 0; ii < 4; ii++) {
            size_t p = (size_t)(bl0 + ty * 4 + ii);
            float4 v = make_float4(acc[ii][0], acc[ii][1], acc[ii][2], acc[ii][3]);
            *(float4*)&Bmb[p * 16 + (tx - 2) * 4] = v;
        }
    } else if (tx < 10) {
        #pragma unroll
        for (int ii = 0; ii < 4; ii++) {
            size_t p = (size_t)(bl0 + ty * 4 + ii);
            float4 v = make_float4(acc[ii][0], acc[ii][1], acc[ii][2], acc[ii][3]);
            *(float4*)&Cmb[p * 16 + (tx - 6) * 4] = v;
        }
    }
    __syncthreads();

    int d = tid;
    float bias = bdt[d];
    float w8[8];
    #pragma unroll
    for (int r = 0; r < 8; r++) w8[r] = wdt[d * 8 + r];
    for (int p = 0; p < 64; p++) {
        float4 xa = *(float4*)&Dt8[p * 8];
        float4 xb = *(float4*)&Dt8[p * 8 + 4];
        float a = bias;
        a += xa.x * w8[0] + xa.y * w8[1] + xa.z * w8[2] + xa.w * w8[3];
        a += xb.x * w8[4] + xb.y * w8[5] + xb.z * w8[6] + xb.w * w8[7];
        float sp = (a > 20.f) ? a : log1pf(__expf(a));
        dtb[(size_t)(bl0 + p) * 256 + d] = sp;
    }
}

// ---------------- K4a: scan phase 1 — per-chunk products & local states ----------------
__global__ __launch_bounds__(256) void k_scan1(const float* __restrict__ dtb,
                                               const float* __restrict__ xin,
                                               const float* __restrict__ Bmb,
                                               const float* __restrict__ Alog,
                                               float* __restrict__ Pb,
                                               float* __restrict__ Sb) {
    int blk = blockIdx.x;            // BATCH*NC blocks
    int b = blk / NC, ch = blk % NC;
    int d = threadIdx.x;
    int t0 = ch * CL;
    __shared__ float Bs[CL * 16];
    for (int idx = threadIdx.x; idx < CL * 16; idx += 256)
        Bs[idx] = Bmb[((size_t)(b * L_SEQ + t0)) * 16 + idx];
    float Ar[16];
    #pragma unroll
    for (int n = 0; n < 16; n++) Ar[n] = -__expf(Alog[d * 16 + n]);
    float P[16], S[16];
    #pragma unroll
    for (int n = 0; n < 16; n++) { P[n] = 1.f; S[n] = 0.f; }
    __syncthreads();
    for (int i = 0; i < CL; i++) {
        size_t p = (size_t)(b * L_SEQ + t0 + i);
        float dtv = dtb[p * 256 + d];
        float xv  = xin[p * 256 + d];
        float du = dtv * xv;
        #pragma unroll
        for (int n = 0; n < 16; n++) {
            float a = __expf(dtv * Ar[n]);
            P[n] *= a;
            S[n] = a * S[n] + du * Bs[i * 16 + n];
        }
    }
    size_t base = ((size_t)(b * NC + ch) * 16) * 256 + d;
    #pragma unroll
    for (int n = 0; n < 16; n++) {
        Pb[base + (size_t)n * 256] = P[n];
        Sb[base + (size_t)n * 256] = S[n];
    }
}

// ---------------- K4b: scan phase 2 — sequential over chunks, Sb becomes h_start ----------------
__global__ __launch_bounds__(256) void k_scan2(const float* __restrict__ Pb,
                                               float* __restrict__ Sb) {
    int id = blockIdx.x * 256 + threadIdx.x;  // 0..8191: (b,n,d)
    int d = id & 255;
    int n = (id >> 8) & 15;
    int b = id >> 12;
    float h = 0.f;
    #pragma unroll 4
    for (int c = 0; c < NC; c++) {
        size_t ix = (((size_t)(b * NC + c) * 16) + n) * 256 + d;
        float Pv = Pb[ix];
        float Sv = Sb[ix];
        Sb[ix] = h;          // h_start for chunk c
        h = Pv * h + Sv;
    }
}

// ---------------- K4c: scan phase 3 — replay chunk, fuse D-skip + silu(z) gate ----------------
__global__ __launch_bounds__(256) void k_scan3(const float* __restrict__ dtb,
                                               const float* __restrict__ xin,
                                               const float* __restrict__ Bmb,
                                               const float* __restrict__ Cmb,
                                               const float* __restrict__ Alog,
                                               const float* __restrict__ Sb,
                                               const float* __restrict__ Dp,
                                               const float* __restrict__ zbuf,
                                               float* __restrict__ yg) {
    int blk = blockIdx.x;
    int b = blk / NC, ch = blk % NC;
    int d = threadIdx.x;
    int t0 = ch * CL;
    __shared__ float Bs[CL * 16], Cs[CL * 16];
    for (int idx = threadIdx.x; idx < CL * 16; idx += 256) {
        Bs[idx] = Bmb[((size_t)(b * L_SEQ + t0)) * 16 + idx];
        Cs[idx] = Cmb[((size_t)(b * L_SEQ + t0)) * 16 + idx];
    }
    float Ar[16], h[16];
    #pragma unroll
    for (int n = 0; n < 16; n++) Ar[n] = -__expf(Alog[d * 16 + n]);
    size_t base = ((size_t)(b * NC + ch) * 16) * 256 + d;
    #pragma unroll
    for (int n = 0; n < 16; n++) h[n] = Sb[base + (size_t)n * 256];
    float Dv = Dp[d];
    __syncthreads();
    for (int i = 0; i < CL; i++) {
        size_t p = (size_t)(b * L_SEQ + t0 + i);
        float dtv = dtb[p * 256 + d];
        float xv  = xin[p * 256 + d];
        float du = dtv * xv;
        float y = 0.f;
        #pragma unroll
        for (int n = 0; n < 16; n++) {
            float a = __expf(dtv * Ar[n]);
            h[n] = a * h[n] + du * Bs[i * 16 + n];
            y += h[n] * Cs[i * 16 + n];
        }
        float zv = zbuf[p * 256 + d];
        float sig = 1.f / (1.f + __expf(-zv));
        yg[p * 256 + d] = (y + xv * Dv) * (zv * sig);
    }
}

// ---------------- K5: out_proj GEMM with transposed output ----------------
__global__ __launch_bounds__(256) void k_outproj(const float* __restrict__ yg,
                                                 const float* __restrict__ wot,
                                                 float* __restrict__ out) {
    // grid: (BL/64, 2)
    __shared__ float As[64 * 68];  // [k][t_local]
    __shared__ float Bs[64 * 68];  // [k][c_local]
    int bl0 = blockIdx.x * 64;
    int b = bl0 / L_SEQ;
    int t0 = bl0 % L_SEQ;
    int c0 = blockIdx.y * 64;
    int tid = threadIdx.x;
    int tx = tid & 15, ty = tid >> 4;   // tx -> t (coalesced out writes), ty -> c

    float acc[4][4] = {};               // [t_off][c_off]
    for (int k0 = 0; k0 < 256; k0 += 64) {
        __syncthreads();
        for (int idx = tid; idx < 64 * 16; idx += 256) {
            int t = idx >> 4, q = idx & 15;
            float4 v = *(const float4*)&yg[(size_t)(bl0 + t) * 256 + k0 + q * 4];
            As[(q * 4 + 0) * 68 + t] = v.x;
            As[(q * 4 + 1) * 68 + t] = v.y;
            As[(q * 4 + 2) * 68 + t] = v.z;
            As[(q * 4 + 3) * 68 + t] = v.w;
        }
        for (int idx = tid; idx < 64 * 16; idx += 256) {
            int kk = idx >> 4, q = idx & 15;
            float4 v = *(const float4*)&wot[(size_t)(k0 + kk) * 128 + c0 + q * 4];
            *(float4*)&Bs[kk * 68 + q * 4] = v;
        }
        __syncthreads();
        for (int k = 0; k < 64; k++) {
            float4 av = *(const float4*)&As[k * 68 + tx * 4];
            float4 bv = *(const float4*)&Bs[k * 68 + ty * 4];
            float a[4] = {av.x, av.y, av.z, av.w};
            float bb[4] = {bv.x, bv.y, bv.z, bv.w};
            #pragma unroll
            for (int ii = 0; ii < 4; ii++)
                #pragma unroll
                for (int jj = 0; jj < 4; jj++) acc[ii][jj] += a[ii] * bb[jj];
        }
    }
    #pragma unroll
    for (int jj = 0; jj < 4; jj++) {
        int c = c0 + ty * 4 + jj;
        float4 v = make_float4(acc[0][jj], acc[1][jj], acc[2][jj], acc[3][jj]);
        *(float4*)&out[((size_t)(b * 128 + c)) * L_SEQ + t0 + tx * 4] = v;
    }
}

extern "C" void kernel_launch(void* const* d_in, const int* in_sizes, int n_in,
                              void* d_out, int out_size, void* d_ws, size_t ws_size,
                              hipStream_t stream) {
    const float* x    = (const float*)d_in[0];
    const float* nw   = (const float*)d_in[1];
    const float* nb   = (const float*)d_in[2];
    const float* w1   = (const float*)d_in[3];
    const float* cw   = (const float*)d_in[4];
    const float* cb   = (const float*)d_in[5];
    const float* wx   = (const float*)d_in[6];
    const float* wdt  = (const float*)d_in[7];
    const float* bdt  = (const float*)d_in[8];
    const float* Alog = (const float*)d_in[9];
    const float* Dp   = (const float*)d_in[10];
    const float* wo   = (const float*)d_in[11];
    float* out = (float*)d_out;

    float* ws   = (float*)d_ws;
    float* zbuf = ws;                       // BL*256
    float* xin  = zbuf + (size_t)BL * 256;  // BL*256
    float* dtb  = xin + (size_t)BL * 256;   // BL*256
    float* Bmb  = dtb + (size_t)BL * 256;   // BL*16
    float* Cmb  = Bmb + (size_t)BL * 16;    // BL*16
    float* Pb   = Cmb + (size_t)BL * 16;    // BATCH*NC*16*256
    float* Sb   = Pb + (size_t)BATCH * NC * 16 * 256;
    float* yg   = Sb + (size_t)BATCH * NC * 16 * 256;  // BL*256
    float* mu   = yg + (size_t)BL * 256;    // BL
    float* rstd = mu + BL;                  // BL
    float* w1t  = rstd + BL;                // 128*512
    float* g    = w1t + 128 * 512;          // 512
    float* h    = g + 512;                  // 512
    float* wxt  = h + 512;                  // 256*64
    float* wot  = wxt + 256 * 64;           // 256*128

    k_prep<<<2, 256, 0, stream>>>(w1, nw, nb, wx, wo, w1t, g, h, wxt, wot);
    k_ln_stats<<<BL / 256, 256, 0, stream>>>(x, mu, rstd);
    k_inproj<<<dim3(BL / 64, 8), 256, 0, stream>>>(x, mu, rstd, w1t, g, h, cw, cb, xin, zbuf);
    k_xproj<<<BL / 64, 256, 0, stream>>>(xin, wxt, wdt, bdt, dtb, Bmb, Cmb);
    k_scan1<<<BATCH * NC, 256, 0, stream>>>(dtb, xin, Bmb, Alog, Pb, Sb);
    k_scan2<<<8192 / 256, 256, 0, stream>>>(Pb, Sb);
    k_scan3<<<BATCH * NC, 256, 0, stream>>>(dtb, xin, Bmb, Cmb, Alog, Sb, Dp, zbuf, yg);
    k_outproj<<<dim3(BL / 64, 2), 256, 0, stream>>>(yg, wot, out);
}